// Round 3
// baseline (307.062 us; speedup 1.0000x reference)
//
#include <hip/hip_runtime.h>

// NT-Xent loss, B=4096, D=256, N=16384, T=0.5.
// loss = mean_i( -pos_i + log(sum_{j!=i} exp(2*dot(zn_i, zn_j)) + 1e-12) )
//
// R5: R4's 4-quadrant phase schedule with three fixes:
//  - 3-bit granule swizzle slot = g ^ (row&7)  (R2-proven, zero bank conflicts)
//  - grid 2048, blocks 0..31 take a second tile (kills the 9th-round tail)
//  - next-tile stages issued in t=3's read-free q2 phase (prologue hides under epilogue)
//  - isdiag epilogue split (no mask ops on off-diag blocks)
//
// ws layout:
//   [0, 8MB)            : zb   — l2-normalized z * 1.6986436, bf16, [16384][256]
//   [8MB, 12MB)         : part — per-colblock row sums, f32, [64][16384]
//   [12MB, 12MB+16KB)   : pospart[4096]
//   [12MB+16KB, +256B)  : logpart[64]
//   [12MB+16KB+256B)    : cnt (uint) — reset to 0 by norm4k every launch

typedef __bf16 bf16;
typedef __bf16 bf16x4 __attribute__((ext_vector_type(4)));
typedef __bf16 bf16x8 __attribute__((ext_vector_type(8)));
typedef float  f32x4  __attribute__((ext_vector_type(4)));

#define NTOT 16384
#define DDIM 256
// sqrt(2*log2(e)) : dot of scaled vectors = 2*log2(e)*dot, so exp2(acc)=exp(2*dot)
#define KSCL 1.6986436f

__device__ __forceinline__ float dot4(float4 a, float4 b) {
    return a.x * b.x + a.y * b.y + a.z * b.z + a.w * b.w;
}

// ---------------- kernel 1: normalize rows -> bf16 (scaled), plus positive-pair sims ----------------
__global__ __launch_bounds__(256) void norm4k(const float* __restrict__ z1,
                                              const float* __restrict__ z2,
                                              const float* __restrict__ z3,
                                              const float* __restrict__ z4,
                                              bf16* __restrict__ zb,
                                              float* __restrict__ pospart,
                                              unsigned* __restrict__ cnt) {
    if (blockIdx.x == 0 && threadIdx.x == 0) *cnt = 0u; // arm last-block-done for rowlogf
    const int wave = threadIdx.x >> 6;
    const int lane = threadIdx.x & 63;
    const int i    = blockIdx.x * 4 + wave; // 0..4095
    const float4* p1 = (const float4*)(z1 + (size_t)i * DDIM);
    const float4* p2 = (const float4*)(z2 + (size_t)i * DDIM);
    const float4* p3 = (const float4*)(z3 + (size_t)i * DDIM);
    const float4* p4 = (const float4*)(z4 + (size_t)i * DDIM);
    float4 a = p1[lane], b = p2[lane], c = p3[lane], d = p4[lane];
    float s11 = dot4(a, a), s22 = dot4(b, b), s33 = dot4(c, c), s44 = dot4(d, d);
    float s12 = dot4(a, b), s23 = dot4(b, c), s34 = dot4(c, d), s41 = dot4(d, a);
#pragma unroll
    for (int m = 32; m >= 1; m >>= 1) {
        s11 += __shfl_xor(s11, m, 64); s22 += __shfl_xor(s22, m, 64);
        s33 += __shfl_xor(s33, m, 64); s44 += __shfl_xor(s44, m, 64);
        s12 += __shfl_xor(s12, m, 64); s23 += __shfl_xor(s23, m, 64);
        s34 += __shfl_xor(s34, m, 64); s41 += __shfl_xor(s41, m, 64);
    }
    const float m1 = fmaxf(sqrtf(s11), 1e-12f), m2 = fmaxf(sqrtf(s22), 1e-12f);
    const float m3 = fmaxf(sqrtf(s33), 1e-12f), m4 = fmaxf(sqrtf(s44), 1e-12f);
    const float i1 = 1.0f / m1, i2 = 1.0f / m2, i3 = 1.0f / m3, i4 = 1.0f / m4;
    const float t1 = i1 * KSCL, t2 = i2 * KSCL, t3 = i3 * KSCL, t4 = i4 * KSCL;
    bf16x4 o;
    o.x = (bf16)(a.x * t1); o.y = (bf16)(a.y * t1); o.z = (bf16)(a.z * t1); o.w = (bf16)(a.w * t1);
    *(bf16x4*)(zb + (size_t)i * DDIM + lane * 4) = o;
    o.x = (bf16)(b.x * t2); o.y = (bf16)(b.y * t2); o.z = (bf16)(b.z * t2); o.w = (bf16)(b.w * t2);
    *(bf16x4*)(zb + (size_t)(i + 4096) * DDIM + lane * 4) = o;
    o.x = (bf16)(c.x * t3); o.y = (bf16)(c.y * t3); o.z = (bf16)(c.z * t3); o.w = (bf16)(c.w * t3);
    *(bf16x4*)(zb + (size_t)(i + 8192) * DDIM + lane * 4) = o;
    o.x = (bf16)(d.x * t4); o.y = (bf16)(d.y * t4); o.z = (bf16)(d.z * t4); o.w = (bf16)(d.w * t4);
    *(bf16x4*)(zb + (size_t)(i + 12288) * DDIM + lane * 4) = o;
    if (lane == 0)
        pospart[i] = 2.0f * (s12 * i1 * i2 + s23 * i2 * i3 + s34 * i3 * i4 + s41 * i4 * i1);
}

// ---------------- epilogue helper (DIAG = compile-time) ----------------
template <bool DIAG>
__device__ __forceinline__ void epilogue(f32x4 (&acc)[8][4], int wr, int wc, int quad, int l15,
                                         float (*rsum)[256], float (*csum)[256]) {
    const int rb = wr << 7;
    const int cb = wc << 6;
    float cs[4] = {0.f, 0.f, 0.f, 0.f};
#pragma unroll
    for (int rt = 0; rt < 8; ++rt) {
        float rs[4] = {0.f, 0.f, 0.f, 0.f};
        const int rtile = rb + (rt << 4);
#pragma unroll
        for (int ct = 0; ct < 4; ++ct) {
            const int ctile = cb + (ct << 4);
#pragma unroll
            for (int r = 0; r < 4; ++r) {
                float e;
                asm("v_exp_f32 %0, %1" : "=v"(e) : "v"(acc[rt][ct][r]));
                if (DIAG) {
                    if ((rtile + (quad << 2) + r) == (ctile + l15)) e = 0.f; // self-sim
                }
                rs[r] += e;
                cs[ct] += e;
            }
        }
#pragma unroll
        for (int m = 1; m <= 8; m <<= 1)
#pragma unroll
            for (int r = 0; r < 4; ++r) rs[r] += __shfl_xor(rs[r], m, 64);
        if (l15 == 0) {
            int lrow = rtile + (quad << 2);
#pragma unroll
            for (int r = 0; r < 4; ++r) rsum[wc][lrow + r] = rs[r];
        }
    }
#pragma unroll
    for (int m = 16; m <= 32; m <<= 1)
#pragma unroll
        for (int ct = 0; ct < 4; ++ct) cs[ct] += __shfl_xor(cs[ct], m, 64);
    if (quad == 0) {
#pragma unroll
        for (int ct = 0; ct < 4; ++ct) csum[wr][cb + (ct << 4) + l15] = cs[ct];
    }
}

// ---------------- kernel 2: fused Gram-matrix exp-rowsum, upper triangle ----------------
__global__ __launch_bounds__(512, 1) void tilek(const bf16* __restrict__ zb,
                                                float* __restrict__ part) {
    // 2 buffers x (A:32KB + B:32KB); 16KB half-regions: A0@0 A1@16K B0@32K B1@48K per buffer
    __shared__ __attribute__((aligned(16))) char lds[131072];
    __shared__ float rsum[4][256];
    __shared__ float csum[2][256];

    const int tid  = threadIdx.x;
    const int wave = tid >> 6;
    const int lane = tid & 63;
    const int quad = lane >> 4;
    const int l15  = lane & 15;
    const int wr   = wave >> 2;   // 0..1  row half (128 rows)
    const int wc   = wave & 3;    // 0..3  col quarter (64 cols)

    // tile assignment: grid 2048; XCD-chunked swizzle; blocks 0..31 take tile 2048+bid too
    const int bid = blockIdx.x;
    int tiles[2];
    tiles[0] = (bid & 7) * 256 + (bid >> 3);
    tiles[1] = 2048 + bid;
    const int nt = (bid < 32) ? 2 : 1;

    auto decode = [](int kk, int& br_, int& bc_) {
        int r = (int)((129.0 - sqrt(16641.0 - 8.0 * (double)kk)) * 0.5);
        if (r > 63) r = 63;
        while (r < 63 && ((r + 1) * 64 - ((r + 1) * r) / 2) <= kk) ++r;
        while (r > 0 && (r * 64 - (r * (r - 1)) / 2) > kk) --r;
        br_ = r;
        bc_ = r + (kk - (r * 64 - (r * (r - 1)) / 2));
    };

    // ---- staging swizzle precompute: slot = g ^ (row&7); source pre-swizzled, dest linear ----
    // dest byte within 16KB half-region: tid*16 (chunk0, rows 0..63) and +8192 (rows 64..127)
    const int r0    = tid >> 3;                       // dest row 0..63
    const int slot0 = tid & 7;
    const int gsw   = slot0 ^ (r0 & 7);               // conceptual granule this lane fetches
    const size_t srcoff = (size_t)r0 * 512 + (size_t)(gsw << 4);

    auto STAGE = [&](const char* gAp, const char* gBp, int t, int h) {
        // h: 0=A rows0-127, 1=A rows128-255, 2=B rows0-127, 3=B rows128-255
        const char* gs = ((h < 2) ? gAp : gBp) + ((h & 1) ? (size_t)(128 * 512) : 0)
                         + srcoff + (size_t)(t << 7);
        char* ld = lds + ((t & 1) << 16) + (h << 14) + tid * 16;
        __builtin_amdgcn_global_load_lds(
            (const __attribute__((address_space(1))) unsigned int*)gs,
            (__attribute__((address_space(3))) unsigned int*)ld, 16, 0, 0);
        __builtin_amdgcn_global_load_lds(
            (const __attribute__((address_space(1))) unsigned int*)(gs + (size_t)(64 * 512)),
            (__attribute__((address_space(3))) unsigned int*)(ld + 8192), 16, 0, 0);
    };

    // ---- per-lane ds_read byte offsets (within a buffer): slot = (quad|4s) ^ (row&7) ----
    // bit2 of the slot is linear in s -> address for s=1 is offX ^ 64.
    const int gq = (quad ^ (l15 & 7)) << 4;
    int offA[8], offB[4];
#pragma unroll
    for (int rt = 0; rt < 8; ++rt)
        offA[rt] = (wr << 14) + ((rt << 4) + l15) * 128 + gq;
#pragma unroll
    for (int ct = 0; ct < 4; ++ct) {
        int br = (wc << 6) + (ct << 4) + l15;
        offB[ct] = 32768 + ((br >> 7) << 14) + (br & 127) * 128 + gq;
    }

    f32x4 zero = {0.f, 0.f, 0.f, 0.f};
    f32x4 acc[8][4];

    // decode + prologue for first tile
    int brow, bcol;
    decode(tiles[0], brow, bcol);
    const char* gA = (const char*)zb + (size_t)brow * 256 * 512;
    const char* gB = (const char*)zb + (size_t)bcol * 256 * 512;
#pragma unroll
    for (int h = 0; h < 4; ++h) STAGE(gA, gB, 0, h);
#pragma unroll
    for (int h = 0; h < 4; ++h) STAGE(gA, gB, 1, h);

    for (int tt = 0; tt < nt; ++tt) {
#pragma unroll
        for (int a = 0; a < 8; ++a)
#pragma unroll
            for (int b = 0; b < 4; ++b) acc[a][b] = zero;

        int nbrow = 0, nbcol = 0;
        const char *ngA = nullptr, *ngB = nullptr;

        asm volatile("s_waitcnt vmcnt(8)" ::: "memory");
        __builtin_amdgcn_s_barrier();

        bf16x8 af[4][2], bfl[2][2], bfh[2][2];

#pragma unroll
        for (int t = 0; t < 4; ++t) {
            const int bo = (t & 1) << 16;

            // ---- phase q0: rt0-3 x ct0-1 (12 reads, 16 MFMA) ----
#pragma unroll
            for (int i = 0; i < 4; ++i)
#pragma unroll
                for (int s = 0; s < 2; ++s)
                    af[i][s] = *(const bf16x8*)(lds + bo + (offA[i] ^ (s << 6)));
#pragma unroll
            for (int j = 0; j < 2; ++j)
#pragma unroll
                for (int s = 0; s < 2; ++s)
                    bfl[j][s] = *(const bf16x8*)(lds + bo + (offB[j] ^ (s << 6)));
            if (t == 1) { STAGE(gA, gB, 2, 0); STAGE(gA, gB, 2, 1); }
            if (t == 2) { STAGE(gA, gB, 3, 0); STAGE(gA, gB, 3, 1); }
            __builtin_amdgcn_s_barrier();
            asm volatile("s_waitcnt lgkmcnt(0)" ::: "memory");
            __builtin_amdgcn_sched_barrier(0);
            __builtin_amdgcn_s_setprio(1);
#pragma unroll
            for (int i = 0; i < 4; ++i)
#pragma unroll
                for (int j = 0; j < 2; ++j)
#pragma unroll
                    for (int s = 0; s < 2; ++s)
                        acc[i][j] = __builtin_amdgcn_mfma_f32_16x16x32_bf16(
                            af[i][s], bfl[j][s], acc[i][j], 0, 0, 0);
            __builtin_amdgcn_s_setprio(0);
            __builtin_amdgcn_s_barrier();

            // ---- phase q1: rt0-3 x ct2-3 (4 reads, af reused) ----
#pragma unroll
            for (int j = 0; j < 2; ++j)
#pragma unroll
                for (int s = 0; s < 2; ++s)
                    bfh[j][s] = *(const bf16x8*)(lds + bo + (offB[2 + j] ^ (s << 6)));
            if (t == 1) { STAGE(gA, gB, 2, 2); STAGE(gA, gB, 2, 3); }
            if (t == 2) { STAGE(gA, gB, 3, 2); STAGE(gA, gB, 3, 3); }
            __builtin_amdgcn_s_barrier();
            asm volatile("s_waitcnt lgkmcnt(0)" ::: "memory");
            __builtin_amdgcn_sched_barrier(0);
            __builtin_amdgcn_s_setprio(1);
#pragma unroll
            for (int i = 0; i < 4; ++i)
#pragma unroll
                for (int j = 0; j < 2; ++j)
#pragma unroll
                    for (int s = 0; s < 2; ++s)
                        acc[i][2 + j] = __builtin_amdgcn_mfma_f32_16x16x32_bf16(
                            af[i][s], bfh[j][s], acc[i][2 + j], 0, 0, 0);
            __builtin_amdgcn_s_setprio(0);
            __builtin_amdgcn_s_barrier();

            // ---- phase q3: rt4-7 x ct2-3 (8 reads: af overwritten; bfh reused) ----
#pragma unroll
            for (int i = 0; i < 4; ++i)
#pragma unroll
                for (int s = 0; s < 2; ++s)
                    af[i][s] = *(const bf16x8*)(lds + bo + (offA[4 + i] ^ (s << 6)));
            __builtin_amdgcn_s_barrier();
            asm volatile("s_waitcnt lgkmcnt(0)" ::: "memory");
            __builtin_amdgcn_sched_barrier(0);
            __builtin_amdgcn_s_setprio(1);
#pragma unroll
            for (int i = 0; i < 4; ++i)
#pragma unroll
                for (int j = 0; j < 2; ++j)
#pragma unroll
                    for (int s = 0; s < 2; ++s)
                        acc[4 + i][2 + j] = __builtin_amdgcn_mfma_f32_16x16x32_bf16(
                            af[i][s], bfh[j][s], acc[4 + i][2 + j], 0, 0, 0);
            __builtin_amdgcn_s_setprio(0);
            __builtin_amdgcn_s_barrier();

            // ---- phase q2: rt4-7 x ct0-1 (0 reads: af + bfl both live) ----
            // t==3: dead-read phase -> issue NEXT tile's 16 stage loads here.
            // Safe: buf0 drained at t=2->3 boundary; buf1 reads complete before q3's
            // trailing barrier (every wave passed its lgkmcnt(0) before that barrier).
            if (t == 3 && tt + 1 < nt) {
                decode(tiles[tt + 1], nbrow, nbcol);
                ngA = (const char*)zb + (size_t)nbrow * 256 * 512;
                ngB = (const char*)zb + (size_t)nbcol * 256 * 512;
#pragma unroll
                for (int h = 0; h < 4; ++h) STAGE(ngA, ngB, 0, h);
#pragma unroll
                for (int h = 0; h < 4; ++h) STAGE(ngA, ngB, 1, h);
            }
            __builtin_amdgcn_s_setprio(1);
#pragma unroll
            for (int i = 0; i < 4; ++i)
#pragma unroll
                for (int j = 0; j < 2; ++j)
#pragma unroll
                    for (int s = 0; s < 2; ++s)
                        acc[4 + i][j] = __builtin_amdgcn_mfma_f32_16x16x32_bf16(
                            af[i][s], bfl[j][s], acc[4 + i][j], 0, 0, 0);
            __builtin_amdgcn_s_setprio(0);
            if (t < 3) { // K-tile boundary gate: next buffer's stages drained, then sync
                asm volatile("s_waitcnt vmcnt(0)" ::: "memory");
                __builtin_amdgcn_s_barrier();
            }
        }

        // epilogue (next tile's stages in flight underneath)
        if (brow == bcol) epilogue<true>(acc, wr, wc, quad, l15, rsum, csum);
        else              epilogue<false>(acc, wr, wc, quad, l15, rsum, csum);
        __syncthreads();
        if (tid < 256) {
            float rv = rsum[0][tid] + rsum[1][tid] + rsum[2][tid] + rsum[3][tid];
            part[(size_t)bcol * NTOT + brow * 256 + tid] = rv;
        } else if (brow != bcol) {
            int c = tid & 255;
            float cv = csum[0][c] + csum[1][c];
            part[(size_t)brow * NTOT + bcol * 256 + c] = cv;
        }
        if (tt + 1 < nt) { brow = nbrow; bcol = nbcol; gA = ngA; gB = ngB; }
    }
}

// ---------------- kernel 3: per-row reduce + log; last block finalizes ----------------
__global__ __launch_bounds__(256) void rowlogf(const float* __restrict__ part,
                                               const float* __restrict__ pospart,
                                               float* __restrict__ logpart,
                                               unsigned* __restrict__ cnt,
                                               float* __restrict__ out) {
    const int row = blockIdx.x * 256 + threadIdx.x;
    float s = 0.f;
#pragma unroll 8
    for (int c = 0; c < 64; ++c) s += part[(size_t)c * NTOT + row];
    float lg = logf(s + 1e-12f);
#pragma unroll
    for (int m = 32; m >= 1; m >>= 1) lg += __shfl_xor(lg, m, 64);
    __shared__ float red[4];
    const int wave = threadIdx.x >> 6, lane = threadIdx.x & 63;
    if (lane == 0) red[wave] = lg;
    __syncthreads();
    if (threadIdx.x == 0) logpart[blockIdx.x] = red[0] + red[1] + red[2] + red[3];

    // last-block-done: winner reduces pospart + logpart
    __shared__ unsigned done;
    __threadfence();
    if (threadIdx.x == 0) done = atomicAdd(cnt, 1u);
    __syncthreads();
    if (done == 63) {
        __threadfence();
        const int t = threadIdx.x;
        float sp = 0.f, sl = 0.f;
        for (int kk = t; kk < 4096; kk += 256) sp += pospart[kk];
        if (t < 64) sl = logpart[t];
#pragma unroll
        for (int m = 32; m >= 1; m >>= 1) { sp += __shfl_xor(sp, m, 64); sl += __shfl_xor(sl, m, 64); }
        __shared__ float rp[4], rl[4];
        if (lane == 0) { rp[wave] = sp; rl[wave] = sl; }
        __syncthreads();
        if (t == 0) {
            float P = rp[0] + rp[1] + rp[2] + rp[3];
            float L = rl[0] + rl[1] + rl[2] + rl[3];
            out[0] = (L - P) / 16384.0f;
        }
    }
}

extern "C" void kernel_launch(void* const* d_in, const int* in_sizes, int n_in,
                              void* d_out, int out_size, void* d_ws, size_t ws_size,
                              hipStream_t stream) {
    const float* z1 = (const float*)d_in[0];
    const float* z2 = (const float*)d_in[1];
    const float* z3 = (const float*)d_in[2];
    const float* z4 = (const float*)d_in[3];
    float* out = (float*)d_out;

    char* ws = (char*)d_ws;
    bf16*  zb      = (bf16*)ws;                                   // 8 MB
    float* part    = (float*)(ws + (size_t)(8u << 20));           // 4 MB
    float* pospart = (float*)(ws + (size_t)(12u << 20));          // 16 KB
    float* logpart = (float*)(ws + (size_t)(12u << 20) + 16384);  // 256 B
    unsigned* cnt  = (unsigned*)(ws + (size_t)(12u << 20) + 16640);

    norm4k<<<1024, 256, 0, stream>>>(z1, z2, z3, z4, zb, pospart, cnt);
    tilek<<<2048, 512, 0, stream>>>(zb, part);
    rowlogf<<<64, 256, 0, stream>>>(part, pospart, logpart, cnt, out);
}

// Round 4
// 209.788 us; speedup vs baseline: 1.4637x; 1.4637x over previous
//
#include <hip/hip_runtime.h>

// NT-Xent loss, B=4096, D=256, N=16384, T=0.5.
// loss = mean_i( -pos_i + log(sum_{j!=i} exp(2*dot(zn_i, zn_j)) + 1e-12) )
//
// R6: 256x128 upper-triangle tiles (C*128 >= R*256), 4160 blocks, 4 waves each
// (2x2, per-wave 128x64). K=256 as 8 K-tiles of 32. Triple-buffered 24KB LDS
// K-tiles, 2-deep prefetch, counted vmcnt(12) gates, 2 raw barriers per K-tile.
// 75KB LDS + <=256 reg/thread -> 2 blocks/CU co-resident (TLP covers barriers).
// LDS: rows packed in pairs -> 128B lines, 8x16B granules, slot = g ^ (line&7)
// (R2-proven conflict-free); inverse swizzle on global source, linear gload_lds dest.
// Diag-straddling tiles (C-2R<=1) mask global_r >= global_c (kills lower tri + self).
// part: flat [4160][384] = 256 row-sums + 128 col-sums per tile; rowlogf walks the
// exact tile sets per row (each sim element counted exactly once).
// exp2-fold: zb scaled by sqrt(2*log2(e)) so epilogue is a bare v_exp_f32.
//
// ws layout:
//   [0, 8MB)             : zb   — l2-normalized z * 1.6986436, bf16, [16384][256]
//   [8MB, 8MB+6.4MB)     : part — f32 [4160][384]
//   [15MB, 15MB+16KB)    : pospart[4096]
//   [15MB+16KB, +256B)   : logpart[64]
//   [15MB+16KB+256B)     : cnt (uint) — reset by norm4k every launch

typedef __bf16 bf16;
typedef __bf16 bf16x4 __attribute__((ext_vector_type(4)));
typedef __bf16 bf16x8 __attribute__((ext_vector_type(8)));
typedef float  f32x4  __attribute__((ext_vector_type(4)));

#define NTOT 16384
#define DDIM 256
// sqrt(2*log2(e)) : dot of scaled vectors = 2*log2(e)*dot, so exp2(acc)=exp(2*dot)
#define KSCL 1.6986436f

__device__ __forceinline__ float dot4(float4 a, float4 b) {
    return a.x * b.x + a.y * b.y + a.z * b.z + a.w * b.w;
}

// ---------------- kernel 1: normalize rows -> bf16 (scaled), plus positive-pair sims ----------------
__global__ __launch_bounds__(256) void norm4k(const float* __restrict__ z1,
                                              const float* __restrict__ z2,
                                              const float* __restrict__ z3,
                                              const float* __restrict__ z4,
                                              bf16* __restrict__ zb,
                                              float* __restrict__ pospart,
                                              unsigned* __restrict__ cnt) {
    if (blockIdx.x == 0 && threadIdx.x == 0) *cnt = 0u; // arm last-block-done for rowlogf
    const int wave = threadIdx.x >> 6;
    const int lane = threadIdx.x & 63;
    const int i    = blockIdx.x * 4 + wave; // 0..4095
    const float4* p1 = (const float4*)(z1 + (size_t)i * DDIM);
    const float4* p2 = (const float4*)(z2 + (size_t)i * DDIM);
    const float4* p3 = (const float4*)(z3 + (size_t)i * DDIM);
    const float4* p4 = (const float4*)(z4 + (size_t)i * DDIM);
    float4 a = p1[lane], b = p2[lane], c = p3[lane], d = p4[lane];
    float s11 = dot4(a, a), s22 = dot4(b, b), s33 = dot4(c, c), s44 = dot4(d, d);
    float s12 = dot4(a, b), s23 = dot4(b, c), s34 = dot4(c, d), s41 = dot4(d, a);
#pragma unroll
    for (int m = 32; m >= 1; m >>= 1) {
        s11 += __shfl_xor(s11, m, 64); s22 += __shfl_xor(s22, m, 64);
        s33 += __shfl_xor(s33, m, 64); s44 += __shfl_xor(s44, m, 64);
        s12 += __shfl_xor(s12, m, 64); s23 += __shfl_xor(s23, m, 64);
        s34 += __shfl_xor(s34, m, 64); s41 += __shfl_xor(s41, m, 64);
    }
    const float m1 = fmaxf(sqrtf(s11), 1e-12f), m2 = fmaxf(sqrtf(s22), 1e-12f);
    const float m3 = fmaxf(sqrtf(s33), 1e-12f), m4 = fmaxf(sqrtf(s44), 1e-12f);
    const float i1 = 1.0f / m1, i2 = 1.0f / m2, i3 = 1.0f / m3, i4 = 1.0f / m4;
    const float t1 = i1 * KSCL, t2 = i2 * KSCL, t3 = i3 * KSCL, t4 = i4 * KSCL;
    bf16x4 o;
    o.x = (bf16)(a.x * t1); o.y = (bf16)(a.y * t1); o.z = (bf16)(a.z * t1); o.w = (bf16)(a.w * t1);
    *(bf16x4*)(zb + (size_t)i * DDIM + lane * 4) = o;
    o.x = (bf16)(b.x * t2); o.y = (bf16)(b.y * t2); o.z = (bf16)(b.z * t2); o.w = (bf16)(b.w * t2);
    *(bf16x4*)(zb + (size_t)(i + 4096) * DDIM + lane * 4) = o;
    o.x = (bf16)(c.x * t3); o.y = (bf16)(c.y * t3); o.z = (bf16)(c.z * t3); o.w = (bf16)(c.w * t3);
    *(bf16x4*)(zb + (size_t)(i + 8192) * DDIM + lane * 4) = o;
    o.x = (bf16)(d.x * t4); o.y = (bf16)(d.y * t4); o.z = (bf16)(d.z * t4); o.w = (bf16)(d.w * t4);
    *(bf16x4*)(zb + (size_t)(i + 12288) * DDIM + lane * 4) = o;
    if (lane == 0)
        pospart[i] = 2.0f * (s12 * i1 * i2 + s23 * i2 * i3 + s34 * i3 * i4 + s41 * i4 * i1);
}

// ---------------- epilogue helper (STRAD = compile-time) ----------------
template <bool STRAD>
__device__ __forceinline__ void epilogue(f32x4 (&acc)[8][4], int Rbase, int Cbase,
                                         int wr, int wc, int quad, int l15,
                                         float (*rsum)[256], float (*csum)[128]) {
    float cs[4] = {0.f, 0.f, 0.f, 0.f};
#pragma unroll
    for (int rt = 0; rt < 8; ++rt) {
        float rs[4] = {0.f, 0.f, 0.f, 0.f};
        const int rloc = (wr << 7) + (rt << 4) + (quad << 2); // + rr = row-local 0..255
#pragma unroll
        for (int ct = 0; ct < 4; ++ct) {
            const int cloc = (wc << 6) + (ct << 4) + l15;     // col-local 0..127
#pragma unroll
            for (int rr = 0; rr < 4; ++rr) {
                float e;
                asm("v_exp_f32 %0, %1" : "=v"(e) : "v"(acc[rt][ct][rr]));
                if (STRAD) {
                    if (Rbase + rloc + rr >= Cbase + cloc) e = 0.f; // lower tri + self
                }
                rs[rr] += e;
                cs[ct] += e;
            }
        }
        // row-sums: reduce across 16 lanes (C-layout: col = lane&15)
#pragma unroll
        for (int m = 1; m <= 8; m <<= 1)
#pragma unroll
            for (int rr = 0; rr < 4; ++rr) rs[rr] += __shfl_xor(rs[rr], m, 64);
        if (l15 == 0) {
#pragma unroll
            for (int rr = 0; rr < 4; ++rr) rsum[wc][rloc + rr] = rs[rr];
        }
    }
    // col-sums: reduce across the 4 quads (rows), lanes 16 apart
#pragma unroll
    for (int m = 16; m <= 32; m <<= 1)
#pragma unroll
        for (int ct = 0; ct < 4; ++ct) cs[ct] += __shfl_xor(cs[ct], m, 64);
    if (quad == 0) {
#pragma unroll
        for (int ct = 0; ct < 4; ++ct) csum[wr][(wc << 6) + (ct << 4) + l15] = cs[ct];
    }
}

// ---------------- kernel 2: fused Gram-matrix exp-rowsum, upper triangle ----------------
__global__ __launch_bounds__(256, 2) void tilek(const bf16* __restrict__ zb,
                                                float* __restrict__ part) {
    // 3 buffers x 24KB (A:16KB + B:8KB each)
    __shared__ __attribute__((aligned(16))) char lds[73728];
    __shared__ float rsum[2][256];
    __shared__ float csum[2][128];

    const int tid  = threadIdx.x;
    const int wave = tid >> 6;
    const int lane = tid & 63;
    const int quad = lane >> 4;
    const int l15  = lane & 15;
    const int wr   = wave >> 1;   // 0..1 row half (128 rows of 256)
    const int wc   = wave & 1;    // 0..1 col half (64 cols of 128)

    // tile decode: k -> (R, C), tiles (R, C) with C >= 2R; f(R) = R*(129-R)
    const int k = blockIdx.x;
    int R = (int)((129.0 - sqrt(16641.0 - 4.0 * (double)k)) * 0.5);
    if (R > 63) R = 63;
    while (R < 63 && (R + 1) * (129 - (R + 1)) <= k) ++R;
    while (R > 0 && R * (129 - R) > k) --R;
    const int C = 2 * R + (k - R * (129 - R));
    const bool strad = (C - 2 * R) <= 1;
    const int Rbase = R << 8;   // global row base
    const int Cbase = C << 7;   // global col base

    const char* gA = (const char*)zb + (size_t)Rbase * 512; // row stride 512B
    const char* gB = (const char*)zb + (size_t)Cbase * 512;

    // ---- staging precompute: pair-packed lines, slot = g ^ (line&7), dest linear ----
    // A: 256 rows -> 128 lines x 128B = 16KB (4 loads/thread)
    // B: 128 rows ->  64 lines x 128B =  8KB (2 loads/thread, region +16384)
    int srcA[4], dstA[4], srcB[2], dstB[2];
#pragma unroll
    for (int i = 0; i < 4; ++i) {
        int d = i * 256 + tid;            // dest granule index 0..1023
        int L = d >> 3, s = d & 7;
        int g = s ^ (L & 7);              // conceptual granule to fetch
        srcA[i] = (2 * L + (g >> 2)) * 512 + ((g & 3) << 4);
        dstA[i] = d << 4;
    }
#pragma unroll
    for (int i = 0; i < 2; ++i) {
        int d = i * 256 + tid;            // 0..511
        int L = d >> 3, s = d & 7;
        int g = s ^ (L & 7);
        srcB[i] = (2 * L + (g >> 2)) * 512 + ((g & 3) << 4);
        dstB[i] = 16384 + (d << 4);
    }

    auto STAGE = [&](int t, int bb) { // t = K-tile (0..7), bb = buffer byte base
#pragma unroll
        for (int i = 0; i < 4; ++i)
            __builtin_amdgcn_global_load_lds(
                (const __attribute__((address_space(1))) unsigned int*)(gA + srcA[i] + t * 64),
                (__attribute__((address_space(3))) unsigned int*)(lds + bb + dstA[i]), 16, 0, 0);
#pragma unroll
        for (int i = 0; i < 2; ++i)
            __builtin_amdgcn_global_load_lds(
                (const __attribute__((address_space(1))) unsigned int*)(gB + srcB[i] + t * 64),
                (__attribute__((address_space(3))) unsigned int*)(lds + bb + dstB[i]), 16, 0, 0);
    };

    // ---- per-lane ds_read byte offsets within a buffer ----
    int offA[8], offB[4];
#pragma unroll
    for (int rt = 0; rt < 8; ++rt) {
        int row = (wr << 7) + (rt << 4) + l15;   // 0..255
        int L = row >> 1;
        int g = ((row & 1) << 2) | quad;
        offA[rt] = (L << 7) + ((g ^ (L & 7)) << 4);
    }
#pragma unroll
    for (int ct = 0; ct < 4; ++ct) {
        int row = (wc << 6) + (ct << 4) + l15;   // 0..127
        int L = row >> 1;
        int g = ((row & 1) << 2) | quad;
        offB[ct] = 16384 + (L << 7) + ((g ^ (L & 7)) << 4);
    }

    f32x4 zero = {0.f, 0.f, 0.f, 0.f};
    f32x4 acc[8][4];
#pragma unroll
    for (int a = 0; a < 8; ++a)
#pragma unroll
        for (int b = 0; b < 4; ++b) acc[a][b] = zero;

    // prologue: stage K-tiles 0,1 into buffers 0,1 (12 loads/thread)
    STAGE(0, 0);
    STAGE(1, 24576);

#pragma unroll
    for (int ko = 0; ko < 8; ++ko) {
        const int base = (ko % 3) * 24576;
        if (ko < 6) STAGE(ko + 2, ((ko + 2) % 3) * 24576); // 2-deep prefetch
        // gate: this K-tile's 6 loads done; 12 newer (2 prefetched tiles) stay in flight
        if (ko < 6)      asm volatile("s_waitcnt vmcnt(12)" ::: "memory");
        else if (ko == 6) asm volatile("s_waitcnt vmcnt(6)" ::: "memory");
        else              asm volatile("s_waitcnt vmcnt(0)" ::: "memory");
        __builtin_amdgcn_s_barrier();      // b1: buf[ko%3] staged by all waves
        __builtin_amdgcn_sched_barrier(0);

        bf16x8 af[8], bfr[4];
#pragma unroll
        for (int rt = 0; rt < 8; ++rt) af[rt] = *(const bf16x8*)(lds + base + offA[rt]);
#pragma unroll
        for (int ct = 0; ct < 4; ++ct) bfr[ct] = *(const bf16x8*)(lds + base + offB[ct]);

        __builtin_amdgcn_s_setprio(1);
#pragma unroll
        for (int rt = 0; rt < 8; ++rt)
#pragma unroll
            for (int ct = 0; ct < 4; ++ct)
                acc[rt][ct] = __builtin_amdgcn_mfma_f32_16x16x32_bf16(
                    af[rt], bfr[ct], acc[rt][ct], 0, 0, 0);
        __builtin_amdgcn_s_setprio(0);
        __builtin_amdgcn_s_barrier();      // b2: all waves done reading buf[ko%3]
        __builtin_amdgcn_sched_barrier(0);
    }

    // epilogue
    if (strad) epilogue<true>(acc, Rbase, Cbase, wr, wc, quad, l15, rsum, csum);
    else       epilogue<false>(acc, Rbase, Cbase, wr, wc, quad, l15, rsum, csum);
    __syncthreads();
    float* pt = part + (size_t)k * 384;
    pt[tid] = rsum[0][tid] + rsum[1][tid];
    if (tid < 128) pt[256 + tid] = csum[0][tid] + csum[1][tid];
}

// ---------------- kernel 3: per-row reduce + log; last block finalizes ----------------
__global__ __launch_bounds__(256) void rowlogf(const float* __restrict__ part,
                                               const float* __restrict__ pospart,
                                               float* __restrict__ logpart,
                                               unsigned* __restrict__ cnt,
                                               float* __restrict__ out) {
    const int r  = blockIdx.x * 256 + threadIdx.x; // 0..16383
    const int R  = r >> 8;
    const int cp = r >> 7;
    const int fR = R * (129 - R);
    float s = 0.f;
    // row-partials: tiles (R, C) for C = 2R..127 -> contiguous idx [fR, fR+128-2R)
    const int n1 = 128 - 2 * R;
    const float* p1 = part + (size_t)fR * 384 + (r & 255);
#pragma unroll 4
    for (int j = 0; j < n1; ++j) s += p1[(size_t)j * 384];
    // col-partials: tiles (R2, cp) for R2 = 0..R; idx(R2) = f(R2) + cp - 2*R2
    int idx = cp; // R2 = 0
    const int c255 = 256 + (r & 127);
    for (int R2 = 0; R2 <= R; ++R2) {
        s += part[(size_t)idx * 384 + c255];
        idx += 126 - 2 * R2;
    }
    float lg = logf(s + 1e-12f);
#pragma unroll
    for (int m = 32; m >= 1; m >>= 1) lg += __shfl_xor(lg, m, 64);
    __shared__ float red[4];
    const int wave = threadIdx.x >> 6, lane = threadIdx.x & 63;
    if (lane == 0) red[wave] = lg;
    __syncthreads();
    if (threadIdx.x == 0) logpart[blockIdx.x] = red[0] + red[1] + red[2] + red[3];

    // last-block-done: winner reduces pospart + logpart
    __shared__ unsigned done;
    __threadfence();
    if (threadIdx.x == 0) done = atomicAdd(cnt, 1u);
    __syncthreads();
    if (done == 63) {
        __threadfence();
        const int t = threadIdx.x;
        float sp = 0.f, sl = 0.f;
        for (int kk = t; kk < 4096; kk += 256) sp += pospart[kk];
        if (t < 64) sl = logpart[t];
#pragma unroll
        for (int m = 32; m >= 1; m >>= 1) { sp += __shfl_xor(sp, m, 64); sl += __shfl_xor(sl, m, 64); }
        __shared__ float rp[4], rl[4];
        if (lane == 0) { rp[wave] = sp; rl[wave] = sl; }
        __syncthreads();
        if (t == 0) {
            float P = rp[0] + rp[1] + rp[2] + rp[3];
            float L = rl[0] + rl[1] + rl[2] + rl[3];
            out[0] = (L - P) / 16384.0f;
        }
    }
}

extern "C" void kernel_launch(void* const* d_in, const int* in_sizes, int n_in,
                              void* d_out, int out_size, void* d_ws, size_t ws_size,
                              hipStream_t stream) {
    const float* z1 = (const float*)d_in[0];
    const float* z2 = (const float*)d_in[1];
    const float* z3 = (const float*)d_in[2];
    const float* z4 = (const float*)d_in[3];
    float* out = (float*)d_out;

    char* ws = (char*)d_ws;
    bf16*  zb      = (bf16*)ws;                                   // 8 MB
    float* part    = (float*)(ws + (size_t)(8u << 20));           // 6.4 MB [4160][384]
    float* pospart = (float*)(ws + (size_t)(15u << 20));          // 16 KB
    float* logpart = (float*)(ws + (size_t)(15u << 20) + 16384);  // 256 B
    unsigned* cnt  = (unsigned*)(ws + (size_t)(15u << 20) + 16640);

    norm4k<<<1024, 256, 0, stream>>>(z1, z2, z3, z4, zb, pospart, cnt);
    tilek<<<4160, 256, 0, stream>>>(zb, part);
    rowlogf<<<64, 256, 0, stream>>>(part, pospart, logpart, cnt, out);
}

// Round 5
// 202.326 us; speedup vs baseline: 1.5177x; 1.0369x over previous
//
#include <hip/hip_runtime.h>

// NT-Xent loss, B=4096, D=256, N=16384, T=0.5.
// loss = mean_i( -pos_i + log(sum_{j!=i} exp(2*dot(zn_i, zn_j)) + 1e-12) )
//
// R7: R6's structure with the spill removed. All staging/read address ARRAYS
// collapsed to base + compile-time immediates (swizzle granule is invariant in
// the unrolled index — proven by mod-8 algebra), and the templated epilogue
// replaced by a single unconditional mask (global_r >= global_c is vacuous for
// non-straddle tiles). Structure unchanged vs R6: 256x128 tiles, 4160 blocks,
// 4 waves (2x2, per-wave 128x64), K=256 as 8 K-tiles of 32, triple-buffered
// 24KB LDS, 2-deep prefetch, counted vmcnt(12), 2 raw barriers/K-tile,
// 2 blocks/CU.
//
// ws layout:
//   [0, 8MB)             : zb   — l2-normalized z * 1.6986436, bf16, [16384][256]
//   [8MB, 8MB+6.4MB)     : part — f32 [4160][384] (256 row-sums + 128 col-sums)
//   [15MB, 15MB+16KB)    : pospart[4096]
//   [15MB+16KB, +256B)   : logpart[64]
//   [15MB+16KB+256B)     : cnt (uint) — reset by norm4k every launch

typedef __bf16 bf16;
typedef __bf16 bf16x4 __attribute__((ext_vector_type(4)));
typedef __bf16 bf16x8 __attribute__((ext_vector_type(8)));
typedef float  f32x4  __attribute__((ext_vector_type(4)));

#define NTOT 16384
#define DDIM 256
// sqrt(2*log2(e)) : dot of scaled vectors = 2*log2(e)*dot, so exp2(acc)=exp(2*dot)
#define KSCL 1.6986436f

__device__ __forceinline__ float dot4(float4 a, float4 b) {
    return a.x * b.x + a.y * b.y + a.z * b.z + a.w * b.w;
}

// ---------------- kernel 1: normalize rows -> bf16 (scaled), plus positive-pair sims ----------------
__global__ __launch_bounds__(256) void norm4k(const float* __restrict__ z1,
                                              const float* __restrict__ z2,
                                              const float* __restrict__ z3,
                                              const float* __restrict__ z4,
                                              bf16* __restrict__ zb,
                                              float* __restrict__ pospart,
                                              unsigned* __restrict__ cnt) {
    if (blockIdx.x == 0 && threadIdx.x == 0) *cnt = 0u; // arm last-block-done for rowlogf
    const int wave = threadIdx.x >> 6;
    const int lane = threadIdx.x & 63;
    const int i    = blockIdx.x * 4 + wave; // 0..4095
    const float4* p1 = (const float4*)(z1 + (size_t)i * DDIM);
    const float4* p2 = (const float4*)(z2 + (size_t)i * DDIM);
    const float4* p3 = (const float4*)(z3 + (size_t)i * DDIM);
    const float4* p4 = (const float4*)(z4 + (size_t)i * DDIM);
    float4 a = p1[lane], b = p2[lane], c = p3[lane], d = p4[lane];
    float s11 = dot4(a, a), s22 = dot4(b, b), s33 = dot4(c, c), s44 = dot4(d, d);
    float s12 = dot4(a, b), s23 = dot4(b, c), s34 = dot4(c, d), s41 = dot4(d, a);
#pragma unroll
    for (int m = 32; m >= 1; m >>= 1) {
        s11 += __shfl_xor(s11, m, 64); s22 += __shfl_xor(s22, m, 64);
        s33 += __shfl_xor(s33, m, 64); s44 += __shfl_xor(s44, m, 64);
        s12 += __shfl_xor(s12, m, 64); s23 += __shfl_xor(s23, m, 64);
        s34 += __shfl_xor(s34, m, 64); s41 += __shfl_xor(s41, m, 64);
    }
    const float m1 = fmaxf(sqrtf(s11), 1e-12f), m2 = fmaxf(sqrtf(s22), 1e-12f);
    const float m3 = fmaxf(sqrtf(s33), 1e-12f), m4 = fmaxf(sqrtf(s44), 1e-12f);
    const float i1 = 1.0f / m1, i2 = 1.0f / m2, i3 = 1.0f / m3, i4 = 1.0f / m4;
    const float t1 = i1 * KSCL, t2 = i2 * KSCL, t3 = i3 * KSCL, t4 = i4 * KSCL;
    bf16x4 o;
    o.x = (bf16)(a.x * t1); o.y = (bf16)(a.y * t1); o.z = (bf16)(a.z * t1); o.w = (bf16)(a.w * t1);
    *(bf16x4*)(zb + (size_t)i * DDIM + lane * 4) = o;
    o.x = (bf16)(b.x * t2); o.y = (bf16)(b.y * t2); o.z = (bf16)(b.z * t2); o.w = (bf16)(b.w * t2);
    *(bf16x4*)(zb + (size_t)(i + 4096) * DDIM + lane * 4) = o;
    o.x = (bf16)(c.x * t3); o.y = (bf16)(c.y * t3); o.z = (bf16)(c.z * t3); o.w = (bf16)(c.w * t3);
    *(bf16x4*)(zb + (size_t)(i + 8192) * DDIM + lane * 4) = o;
    o.x = (bf16)(d.x * t4); o.y = (bf16)(d.y * t4); o.z = (bf16)(d.z * t4); o.w = (bf16)(d.w * t4);
    *(bf16x4*)(zb + (size_t)(i + 12288) * DDIM + lane * 4) = o;
    if (lane == 0)
        pospart[i] = 2.0f * (s12 * i1 * i2 + s23 * i2 * i3 + s34 * i3 * i4 + s41 * i4 * i1);
}

// ---------------- kernel 2: fused Gram-matrix exp-rowsum, upper triangle ----------------
__global__ __launch_bounds__(256, 2) void tilek(const bf16* __restrict__ zb,
                                                float* __restrict__ part) {
    // 3 buffers x 24KB (A:16KB + B:8KB each)
    __shared__ __attribute__((aligned(16))) char lds[73728];
    __shared__ float rsum[2][256];
    __shared__ float csum[2][128];

    const int tid  = threadIdx.x;
    const int wave = tid >> 6;
    const int lane = tid & 63;
    const int quad = lane >> 4;
    const int l15  = lane & 15;
    const int wr   = wave >> 1;   // 0..1 row half (128 rows of 256)
    const int wc   = wave & 1;    // 0..1 col half (64 cols of 128)

    // tile decode: k -> (R, C), tiles (R, C) with C >= 2R; f(R) = R*(129-R)
    const int k = blockIdx.x;
    int R = (int)((129.0 - sqrt(16641.0 - 4.0 * (double)k)) * 0.5);
    if (R > 63) R = 63;
    while (R < 63 && (R + 1) * (129 - (R + 1)) <= k) ++R;
    while (R > 0 && R * (129 - R) > k) --R;
    const int C = 2 * R + (k - R * (129 - R));
    const int Rbase = R << 8;   // global row base
    const int Cbase = C << 7;   // global col base
    const int dRC   = Rbase - Cbase; // mask arithmetic; >= 0 possible only when straddling

    // ---- staging addressing (collapsed): pair-packed 128B lines, slot = g ^ (line&7) ----
    // chunk i (i<4 for A, i<2 for B): dest granule d = i*256+tid, line = i*32+(tid>>3),
    // slot = tid&7. Since i*32 === 0 (mod 8), the swizzle granule g is i-invariant:
    //   src(i) = src0 + i*32768, dst(i) = tid*16 + i*4096.
    const int dL = tid >> 3;                 // line within chunk, 0..31
    const int dG = (tid & 7) ^ (dL & 7);     // conceptual granule this lane fetches
    const int srcoff = (2 * dL + (dG >> 2)) * 512 + ((dG & 3) << 4);
    const char* gA0 = (const char*)zb + (size_t)Rbase * 512 + srcoff;
    const char* gB0 = (const char*)zb + (size_t)Cbase * 512 + srcoff;
    const int dst0 = tid << 4;

    auto STAGE = [&](int t, int bb) { // t = K-tile (0..7) -> +t*64 bytes; bb = buffer base
#pragma unroll
        for (int i = 0; i < 4; ++i)
            __builtin_amdgcn_global_load_lds(
                (const __attribute__((address_space(1))) unsigned int*)(gA0 + (i << 15) + (t << 6)),
                (__attribute__((address_space(3))) unsigned int*)(lds + bb + (i << 12) + dst0),
                16, 0, 0);
#pragma unroll
        for (int i = 0; i < 2; ++i)
            __builtin_amdgcn_global_load_lds(
                (const __attribute__((address_space(1))) unsigned int*)(gB0 + (i << 15) + (t << 6)),
                (__attribute__((address_space(3))) unsigned int*)(lds + bb + 16384 + (i << 12) + dst0),
                16, 0, 0);
    };

    // ---- ds_read addressing (collapsed): off(rt) = off0 + rt*1024 ----
    // row(rt) = base + rt*16 + l15 -> line advances by 8 -> line&7 and granule invariant.
    const int Lg    = l15 >> 1;
    const int gg    = ((l15 & 1) << 2) | quad;
    const int sw    = (gg ^ Lg) << 4;
    const int offA0 = (((wr << 6) + Lg) << 7) + sw;
    const int offB0 = 16384 + (((wc << 5) + Lg) << 7) + sw;

    f32x4 zero = {0.f, 0.f, 0.f, 0.f};
    f32x4 acc[8][4];
#pragma unroll
    for (int a = 0; a < 8; ++a)
#pragma unroll
        for (int b = 0; b < 4; ++b) acc[a][b] = zero;

    // prologue: stage K-tiles 0,1 into buffers 0,1 (12 loads/thread)
    STAGE(0, 0);
    STAGE(1, 24576);

#pragma unroll
    for (int ko = 0; ko < 8; ++ko) {
        const int base = (ko % 3) * 24576;
        if (ko < 6) STAGE(ko + 2, ((ko + 2) % 3) * 24576); // 2-deep prefetch
        // gate: this K-tile's 6 loads done; 12 newer (2 prefetched tiles) stay in flight
        if (ko < 6)       asm volatile("s_waitcnt vmcnt(12)" ::: "memory");
        else if (ko == 6) asm volatile("s_waitcnt vmcnt(6)" ::: "memory");
        else              asm volatile("s_waitcnt vmcnt(0)" ::: "memory");
        __builtin_amdgcn_s_barrier();      // b1: buf[ko%3] staged by all waves
        __builtin_amdgcn_sched_barrier(0);

        bf16x8 af[8], bfr[4];
#pragma unroll
        for (int rt = 0; rt < 8; ++rt)
            af[rt] = *(const bf16x8*)(lds + base + offA0 + (rt << 10));
#pragma unroll
        for (int ct = 0; ct < 4; ++ct)
            bfr[ct] = *(const bf16x8*)(lds + base + offB0 + (ct << 10));

        __builtin_amdgcn_s_setprio(1);
#pragma unroll
        for (int rt = 0; rt < 8; ++rt)
#pragma unroll
            for (int ct = 0; ct < 4; ++ct)
                acc[rt][ct] = __builtin_amdgcn_mfma_f32_16x16x32_bf16(
                    af[rt], bfr[ct], acc[rt][ct], 0, 0, 0);
        __builtin_amdgcn_s_setprio(0);
        __builtin_amdgcn_s_barrier();      // b2: all waves done reading buf[ko%3]
        __builtin_amdgcn_sched_barrier(0);
    }

    // epilogue: e = exp2(acc) = exp(2*dot); mask global_r >= global_c.
    // For non-straddle tiles (C >= 2R+2): Rbase+255 < Cbase, so the mask is vacuous —
    // one unconditional compare per element, no branch, no code duplication.
    float cs[4] = {0.f, 0.f, 0.f, 0.f};
#pragma unroll
    for (int rt = 0; rt < 8; ++rt) {
        float rs[4] = {0.f, 0.f, 0.f, 0.f};
        const int rloc = (wr << 7) + (rt << 4) + (quad << 2); // + rr = row-local 0..255
#pragma unroll
        for (int ct = 0; ct < 4; ++ct) {
            const int cloc = (wc << 6) + (ct << 4) + l15;     // col-local 0..127
#pragma unroll
            for (int rr = 0; rr < 4; ++rr) {
                float e;
                asm("v_exp_f32 %0, %1" : "=v"(e) : "v"(acc[rt][ct][rr]));
                if (rloc + rr + dRC >= cloc) e = 0.f; // lower tri + self (vacuous off-diag)
                rs[rr] += e;
                cs[ct] += e;
            }
        }
        // row-sums: reduce across 16 lanes (C-layout: col = lane&15)
#pragma unroll
        for (int m = 1; m <= 8; m <<= 1)
#pragma unroll
            for (int rr = 0; rr < 4; ++rr) rs[rr] += __shfl_xor(rs[rr], m, 64);
        if (l15 == 0) {
#pragma unroll
            for (int rr = 0; rr < 4; ++rr) rsum[wc][rloc + rr] = rs[rr];
        }
    }
    // col-sums: reduce across the 4 quads (rows), lanes 16 apart
#pragma unroll
    for (int m = 16; m <= 32; m <<= 1)
#pragma unroll
        for (int ct = 0; ct < 4; ++ct) cs[ct] += __shfl_xor(cs[ct], m, 64);
    if (quad == 0) {
#pragma unroll
        for (int ct = 0; ct < 4; ++ct) csum[wr][(wc << 6) + (ct << 4) + l15] = cs[ct];
    }
    __syncthreads();
    float* pt = part + (size_t)k * 384;
    pt[tid] = rsum[0][tid] + rsum[1][tid];
    if (tid < 128) pt[256 + tid] = csum[0][tid] + csum[1][tid];
}

// ---------------- kernel 3: per-row reduce + log; last block finalizes ----------------
__global__ __launch_bounds__(256) void rowlogf(const float* __restrict__ part,
                                               const float* __restrict__ pospart,
                                               float* __restrict__ logpart,
                                               unsigned* __restrict__ cnt,
                                               float* __restrict__ out) {
    const int r  = blockIdx.x * 256 + threadIdx.x; // 0..16383
    const int R  = r >> 8;
    const int cp = r >> 7;
    const int fR = R * (129 - R);
    float s = 0.f;
    // row-partials: tiles (R, C) for C = 2R..127 -> contiguous idx [fR, fR+128-2R)
    const int n1 = 128 - 2 * R;
    const float* p1 = part + (size_t)fR * 384 + (r & 255);
#pragma unroll 4
    for (int j = 0; j < n1; ++j) s += p1[(size_t)j * 384];
    // col-partials: tiles (R2, cp) for R2 = 0..R; idx(R2) = f(R2) + cp - 2*R2
    int idx = cp; // R2 = 0
    const int c255 = 256 + (r & 127);
    for (int R2 = 0; R2 <= R; ++R2) {
        s += part[(size_t)idx * 384 + c255];
        idx += 126 - 2 * R2;
    }
    float lg = logf(s + 1e-12f);
#pragma unroll
    for (int m = 32; m >= 1; m >>= 1) lg += __shfl_xor(lg, m, 64);
    __shared__ float red[4];
    const int wave = threadIdx.x >> 6, lane = threadIdx.x & 63;
    if (lane == 0) red[wave] = lg;
    __syncthreads();
    if (threadIdx.x == 0) logpart[blockIdx.x] = red[0] + red[1] + red[2] + red[3];

    // last-block-done: winner reduces pospart + logpart
    __shared__ unsigned done;
    __threadfence();
    if (threadIdx.x == 0) done = atomicAdd(cnt, 1u);
    __syncthreads();
    if (done == 63) {
        __threadfence();
        const int t = threadIdx.x;
        float sp = 0.f, sl = 0.f;
        for (int kk = t; kk < 4096; kk += 256) sp += pospart[kk];
        if (t < 64) sl = logpart[t];
#pragma unroll
        for (int m = 32; m >= 1; m >>= 1) { sp += __shfl_xor(sp, m, 64); sl += __shfl_xor(sl, m, 64); }
        __shared__ float rp[4], rl[4];
        if (lane == 0) { rp[wave] = sp; rl[wave] = sl; }
        __syncthreads();
        if (t == 0) {
            float P = rp[0] + rp[1] + rp[2] + rp[3];
            float L = rl[0] + rl[1] + rl[2] + rl[3];
            out[0] = (L - P) / 16384.0f;
        }
    }
}

extern "C" void kernel_launch(void* const* d_in, const int* in_sizes, int n_in,
                              void* d_out, int out_size, void* d_ws, size_t ws_size,
                              hipStream_t stream) {
    const float* z1 = (const float*)d_in[0];
    const float* z2 = (const float*)d_in[1];
    const float* z3 = (const float*)d_in[2];
    const float* z4 = (const float*)d_in[3];
    float* out = (float*)d_out;

    char* ws = (char*)d_ws;
    bf16*  zb      = (bf16*)ws;                                   // 8 MB
    float* part    = (float*)(ws + (size_t)(8u << 20));           // 6.4 MB [4160][384]
    float* pospart = (float*)(ws + (size_t)(15u << 20));          // 16 KB
    float* logpart = (float*)(ws + (size_t)(15u << 20) + 16384);  // 256 B
    unsigned* cnt  = (unsigned*)(ws + (size_t)(15u << 20) + 16640);

    norm4k<<<1024, 256, 0, stream>>>(z1, z2, z3, z4, zb, pospart, cnt);
    tilek<<<4160, 256, 0, stream>>>(zb, part);
    rowlogf<<<64, 256, 0, stream>>>(part, pospart, logpart, cnt, out);
}